// Round 3
// baseline (1151.057 us; speedup 1.0000x reference)
//
#include <hip/hip_runtime.h>
#include <hip/hip_bf16.h>

#define SEQ 512
#define HID 768
#define HEADS 12
#define DH 64
#define LAYERS 12
#define BATCH 32
#define TOK (BATCH*SEQ)   // 16384

typedef __hip_bfloat16 hbf16;
typedef __attribute__((ext_vector_type(8))) __bf16 bf16x8;
typedef __attribute__((ext_vector_type(4))) __bf16 bf16x4;
typedef __attribute__((ext_vector_type(4))) float f32x4;

// ---------------- embed + layernorm: fp32 in -> bf16 h[tok][c] ----------------
__global__ __launch_bounds__(256) void embed_ln_k(
    const int* __restrict__ x, const float* __restrict__ we,
    const float* __restrict__ pe, const float* __restrict__ te,
    const float* __restrict__ g, const float* __restrict__ be,
    __bf16* __restrict__ h) {
  const int tok = blockIdx.x;
  const int s = tok & (SEQ - 1);
  const int wid = x[tok];
  const int tid = threadIdx.x;
  float v[3];
  float sum = 0.f, sq = 0.f;
#pragma unroll
  for (int j = 0; j < 3; j++) {
    int c = tid + j * 256;
    float val = we[(size_t)wid * HID + c] + pe[(size_t)s * HID + c] + te[c];
    v[j] = val; sum += val; sq += val * val;
  }
#pragma unroll
  for (int off = 32; off > 0; off >>= 1) {
    sum += __shfl_down(sum, off);
    sq  += __shfl_down(sq, off);
  }
  __shared__ float rs_[4], rq_[4];
  const int wv = tid >> 6;
  if ((tid & 63) == 0) { rs_[wv] = sum; rq_[wv] = sq; }
  __syncthreads();
  sum = rs_[0] + rs_[1] + rs_[2] + rs_[3];
  sq  = rq_[0] + rq_[1] + rq_[2] + rq_[3];
  const float mu  = sum * (1.f / HID);
  const float var = sq * (1.f / HID) - mu * mu;
  const float inv = rsqrtf(var + 1e-12f);
#pragma unroll
  for (int j = 0; j < 3; j++) {
    int c = tid + j * 256;
    float o = (v[j] - mu) * inv * g[c] + be[c];
    h[(size_t)tok * HID + c] = (__bf16)o;
  }
}

// ---------------- per-layer M transpose+convert: Mt[head][t][s] = bf16(M[head][s][t]) ----------------
__global__ __launch_bounds__(256) void transpose_m_k(
    const float* __restrict__ Ml, __bf16* __restrict__ Mt) {
  __shared__ float tile[64][68];            // +4 pad
  const int head = blockIdx.z;
  const int t0 = blockIdx.x * 64, s0 = blockIdx.y * 64;
  const float* src = Ml + (size_t)head * SEQ * SEQ;
  __bf16* dst = Mt + (size_t)head * SEQ * SEQ;
  const int tid = threadIdx.x;
#pragma unroll
  for (int it = 0; it < 4; it++) {          // 64*64 fp32 / (256*4) = 4 passes
    int e = (it * 256 + tid) * 4;
    int r = e >> 6, c = e & 63;             // tile[r=s][c=t]
    *(f32x4*)&tile[r][c] = *(const f32x4*)&src[(size_t)(s0 + r) * SEQ + t0 + c];
  }
  __syncthreads();
#pragma unroll
  for (int it = 0; it < 2; it++) {          // 64*64 bf16 / (256*8) = 2 passes
    int e = (it * 256 + tid) * 8;
    int r = e >> 6, c = e & 63;             // out row t=t0+r, cols s0+c..+8
    bf16x8 vv;
#pragma unroll
    for (int j = 0; j < 8; j++) vv[j] = (__bf16)tile[c + j][r];
    *(bf16x8*)&dst[(size_t)(t0 + r) * SEQ + s0 + c] = vv;
  }
}

// ---------------- flipped dense: h2t[dout][tok] = sum_k W[dout][k]*h[tok][k] ----------------
__global__ __launch_bounds__(256) void dense_t_k(
    const float* __restrict__ Wl, const __bf16* __restrict__ hin,
    __bf16* __restrict__ h2t) {
  __shared__ __bf16 Al[128][40];            // W rows (m = dout), +8 pad
  __shared__ __bf16 Bl[128][40];            // h rows (n = tok)
  const int n0 = blockIdx.x * 128;          // token base
  const int m0 = blockIdx.y * 128;          // dout base
  const int tid = threadIdx.x;
  const int wave = tid >> 6, lane = tid & 63;
  const int wm = (wave >> 1) << 6, wn = (wave & 1) << 6;
  const int lm = lane & 15, q = lane >> 4;
  f32x4 acc[4][4];
#pragma unroll
  for (int i = 0; i < 4; i++)
#pragma unroll
    for (int j = 0; j < 4; j++) acc[i][j] = {0.f, 0.f, 0.f, 0.f};

  for (int k0 = 0; k0 < HID; k0 += 32) {
    // A: fp32 source, 4096 elems / (256*4) = 4 passes, convert to bf16
#pragma unroll
    for (int it = 0; it < 4; it++) {
      int e = (it * 256 + tid) * 4;
      int r = e >> 5, c = e & 31;
      f32x4 w4 = *(const f32x4*)&Wl[(size_t)(m0 + r) * HID + k0 + c];
      bf16x4 b4;
#pragma unroll
      for (int j = 0; j < 4; j++) b4[j] = (__bf16)w4[j];
      *(bf16x4*)&Al[r][c] = b4;
    }
    // B: bf16 source, 4096 elems / (256*8) = 2 passes
#pragma unroll
    for (int it = 0; it < 2; it++) {
      int e = (it * 256 + tid) * 8;
      int r = e >> 5, c = e & 31;
      *(bf16x8*)&Bl[r][c] = *(const bf16x8*)&hin[(size_t)(n0 + r) * HID + k0 + c];
    }
    __syncthreads();
    bf16x8 af[4], bfr[4];
#pragma unroll
    for (int i = 0; i < 4; i++) {
      af[i]  = *(const bf16x8*)&Al[wm + i * 16 + lm][q * 8];
      bfr[i] = *(const bf16x8*)&Bl[wn + i * 16 + lm][q * 8];
    }
#pragma unroll
    for (int mi = 0; mi < 4; mi++)
#pragma unroll
      for (int ni = 0; ni < 4; ni++)
        acc[mi][ni] = __builtin_amdgcn_mfma_f32_16x16x32_bf16(af[mi], bfr[ni], acc[mi][ni], 0, 0, 0);
    __syncthreads();
  }
  // D layout: row(m)=q*4+r, col(n)=lm  [verified m89/m91]
#pragma unroll
  for (int mi = 0; mi < 4; mi++)
#pragma unroll
    for (int ni = 0; ni < 4; ni++)
#pragma unroll
      for (int r = 0; r < 4; r++) {
        int dout = m0 + wm + mi * 16 + q * 4 + r;
        int n = n0 + wn + ni * 16 + lm;
        h2t[(size_t)dout * TOK + n] = (__bf16)acc[mi][ni][r];
      }
}

// ---------------- mixing + bias + relu ----------------
// C[t][d] = sum_s Mt[head][t][s] * h2t[head*64+d][b*512+s];  hout[b][t][head*64+d]=relu(C+bias)
__global__ __launch_bounds__(256) void mix_relu_k(
    const __bf16* __restrict__ Mt, const __bf16* __restrict__ h2t,
    const float* __restrict__ bias_l, __bf16* __restrict__ hout) {
  __shared__ __bf16 Al[256][40];            // Mt rows (m = t)
  __shared__ __bf16 Bl[64][40];             // h2t rows (n = d)
  const int t0 = blockIdx.x * 256;
  const int head = blockIdx.y;
  const int b = blockIdx.z;
  const __bf16* Mh = Mt + (size_t)head * SEQ * SEQ;
  const __bf16* X  = h2t + (size_t)head * DH * TOK + (size_t)b * SEQ;
  const int tid = threadIdx.x;
  const int wave = tid >> 6, lane = tid & 63;
  const int wm = wave << 6;                 // 4 waves x 64 t-rows
  const int lm = lane & 15, q = lane >> 4;
  f32x4 acc[4][4];
#pragma unroll
  for (int i = 0; i < 4; i++)
#pragma unroll
    for (int j = 0; j < 4; j++) acc[i][j] = {0.f, 0.f, 0.f, 0.f};

  for (int s0 = 0; s0 < SEQ; s0 += 32) {
    // A: 256x32 = 8192 -> 4 passes
#pragma unroll
    for (int it = 0; it < 4; it++) {
      int e = (it * 256 + tid) * 8;
      int r = e >> 5, c = e & 31;
      *(bf16x8*)&Al[r][c] = *(const bf16x8*)&Mh[(size_t)(t0 + r) * SEQ + s0 + c];
    }
    // B: 64x32 = 2048 -> 1 pass
    {
      int e = tid * 8;
      int r = e >> 5, c = e & 31;
      *(bf16x8*)&Bl[r][c] = *(const bf16x8*)&X[(size_t)r * TOK + s0 + c];
    }
    __syncthreads();
    bf16x8 af[4], bfr[4];
#pragma unroll
    for (int i = 0; i < 4; i++) {
      af[i]  = *(const bf16x8*)&Al[wm + i * 16 + lm][q * 8];
      bfr[i] = *(const bf16x8*)&Bl[i * 16 + lm][q * 8];
    }
#pragma unroll
    for (int mi = 0; mi < 4; mi++)
#pragma unroll
      for (int ni = 0; ni < 4; ni++)
        acc[mi][ni] = __builtin_amdgcn_mfma_f32_16x16x32_bf16(af[mi], bfr[ni], acc[mi][ni], 0, 0, 0);
    __syncthreads();
  }
  float bias[4];
#pragma unroll
  for (int ni = 0; ni < 4; ni++) bias[ni] = bias_l[head * DH + ni * 16 + lm];
#pragma unroll
  for (int mi = 0; mi < 4; mi++)
#pragma unroll
    for (int ni = 0; ni < 4; ni++)
#pragma unroll
      for (int r = 0; r < 4; r++) {
        int t = t0 + wm + mi * 16 + q * 4 + r;
        float vv = fmaxf(acc[mi][ni][r] + bias[ni], 0.f);
        hout[((size_t)b * SEQ + t) * HID + head * DH + ni * 16 + lm] = (__bf16)vv;
      }
}

// ---------------- final dense: out[tok][dout] = sum_k h[tok][k]*lw[dout][k] + lb (fp32 out) ----------------
__global__ __launch_bounds__(256) void dense_nat_k(
    const __bf16* __restrict__ hin, const float* __restrict__ lw,
    const float* __restrict__ lb, float* __restrict__ out) {
  __shared__ __bf16 Al[128][40];            // h rows (m = tok)
  __shared__ __bf16 Bl[128][40];            // lw rows (n = dout)
  const int m0 = blockIdx.x * 128;
  const int n0 = blockIdx.y * 128;
  const int tid = threadIdx.x;
  const int wave = tid >> 6, lane = tid & 63;
  const int wm = (wave >> 1) << 6, wn = (wave & 1) << 6;
  const int lm = lane & 15, q = lane >> 4;
  f32x4 acc[4][4];
#pragma unroll
  for (int i = 0; i < 4; i++)
#pragma unroll
    for (int j = 0; j < 4; j++) acc[i][j] = {0.f, 0.f, 0.f, 0.f};

  for (int k0 = 0; k0 < HID; k0 += 32) {
#pragma unroll
    for (int it = 0; it < 2; it++) {        // A: bf16, 2 passes
      int e = (it * 256 + tid) * 8;
      int r = e >> 5, c = e & 31;
      *(bf16x8*)&Al[r][c] = *(const bf16x8*)&hin[(size_t)(m0 + r) * HID + k0 + c];
    }
#pragma unroll
    for (int it = 0; it < 4; it++) {        // B: fp32 -> bf16, 4 passes
      int e = (it * 256 + tid) * 4;
      int r = e >> 5, c = e & 31;
      f32x4 w4 = *(const f32x4*)&lw[(size_t)(n0 + r) * HID + k0 + c];
      bf16x4 b4;
#pragma unroll
      for (int j = 0; j < 4; j++) b4[j] = (__bf16)w4[j];
      *(bf16x4*)&Bl[r][c] = b4;
    }
    __syncthreads();
    bf16x8 af[4], bfr[4];
#pragma unroll
    for (int i = 0; i < 4; i++) {
      af[i]  = *(const bf16x8*)&Al[wm + i * 16 + lm][q * 8];
      bfr[i] = *(const bf16x8*)&Bl[wn + i * 16 + lm][q * 8];
    }
#pragma unroll
    for (int mi = 0; mi < 4; mi++)
#pragma unroll
      for (int ni = 0; ni < 4; ni++)
        acc[mi][ni] = __builtin_amdgcn_mfma_f32_16x16x32_bf16(af[mi], bfr[ni], acc[mi][ni], 0, 0, 0);
    __syncthreads();
  }
#pragma unroll
  for (int mi = 0; mi < 4; mi++)
#pragma unroll
    for (int ni = 0; ni < 4; ni++) {
      float bias = lb[n0 + wn + ni * 16 + lm];
#pragma unroll
      for (int r = 0; r < 4; r++) {
        int tok = m0 + wm + mi * 16 + q * 4 + r;
        int n = n0 + wn + ni * 16 + lm;
        out[(size_t)tok * HID + n] = acc[mi][ni][r] + bias;
      }
    }
}

extern "C" void kernel_launch(void* const* d_in, const int* in_sizes, int n_in,
                              void* d_out, int out_size, void* d_ws, size_t ws_size,
                              hipStream_t stream) {
  const int*   x   = (const int*)d_in[0];
  const float* we  = (const float*)d_in[1];
  const float* pe  = (const float*)d_in[2];
  const float* te  = (const float*)d_in[3];
  const float* lng = (const float*)d_in[4];
  const float* lnb = (const float*)d_in[5];
  const float* W   = (const float*)d_in[6];   // [12][768][768]
  const float* bb  = (const float*)d_in[7];   // [12][768]
  const float* M   = (const float*)d_in[8];   // [12][12][512][512]
  const float* lw  = (const float*)d_in[9];
  const float* lb  = (const float*)d_in[10];

  // workspace (bf16): Mt (one layer) | hA token-major | h2t feature-major = 56.6 MB
  __bf16* Mt  = (__bf16*)d_ws;                     // 12*512*512
  __bf16* hA  = Mt + (size_t)HEADS * SEQ * SEQ;    // 16384*768
  __bf16* h2t = hA + (size_t)TOK * HID;            // 768*16384
  float* out = (float*)d_out;

  embed_ln_k<<<TOK, 256, 0, stream>>>(x, we, pe, te, lng, lnb, hA);
  for (int l = 0; l < LAYERS; l++) {
    transpose_m_k<<<dim3(8, 8, HEADS), 256, 0, stream>>>(M + (size_t)l * HEADS * SEQ * SEQ, Mt);
    dense_t_k<<<dim3(TOK / 128, HID / 128), 256, 0, stream>>>(W + (size_t)l * HID * HID, hA, h2t);
    mix_relu_k<<<dim3(2, HEADS, BATCH), 256, 0, stream>>>(Mt, h2t, bb + (size_t)l * HID, hA);
  }
  dense_nat_k<<<dim3(TOK / 128, HID / 128), 256, 0, stream>>>(hA, lw, lb, out);
}

// Round 4
// 1017.935 us; speedup vs baseline: 1.1308x; 1.1308x over previous
//
#include <hip/hip_runtime.h>
#include <hip/hip_bf16.h>

#define SEQ 512
#define HID 768
#define HEADS 12
#define DH 64
#define LAYERS 12
#define BATCH 32
#define TOK (BATCH*SEQ)   // 16384

typedef __attribute__((ext_vector_type(8))) __bf16 bf16x8;
typedef __attribute__((ext_vector_type(4))) __bf16 bf16x4;
typedef __attribute__((ext_vector_type(4))) float f32x4;

typedef __attribute__((address_space(1))) const void gvoid;
typedef __attribute__((address_space(3))) void svoid;
// async global->LDS, 16B/lane; LDS dest must be wave-uniform base + lane*16 [m97/m104]
__device__ __forceinline__ void async_cp16(const void* g, void* l) {
  __builtin_amdgcn_global_load_lds((gvoid*)g, (svoid*)l, 16, 0, 0);
}

// ---------------- fp32 -> bf16 bulk convert (W, last_w) ----------------
__global__ __launch_bounds__(256) void convert_k(
    const float* __restrict__ src, __bf16* __restrict__ dst) {
  int i = (blockIdx.x * 256 + threadIdx.x) * 4;
  f32x4 v = *(const f32x4*)&src[i];
  bf16x4 b;
#pragma unroll
  for (int j = 0; j < 4; j++) b[j] = (__bf16)v[j];
  *(bf16x4*)&dst[i] = b;
}

// ---------------- embed + layernorm: fp32 in -> bf16 h[tok][c] ----------------
__global__ __launch_bounds__(256) void embed_ln_k(
    const int* __restrict__ x, const float* __restrict__ we,
    const float* __restrict__ pe, const float* __restrict__ te,
    const float* __restrict__ g, const float* __restrict__ be,
    __bf16* __restrict__ h) {
  const int tok = blockIdx.x;
  const int s = tok & (SEQ - 1);
  const int wid = x[tok];
  const int tid = threadIdx.x;
  float v[3];
  float sum = 0.f, sq = 0.f;
#pragma unroll
  for (int j = 0; j < 3; j++) {
    int c = tid + j * 256;
    float val = we[(size_t)wid * HID + c] + pe[(size_t)s * HID + c] + te[c];
    v[j] = val; sum += val; sq += val * val;
  }
#pragma unroll
  for (int off = 32; off > 0; off >>= 1) {
    sum += __shfl_down(sum, off);
    sq  += __shfl_down(sq, off);
  }
  __shared__ float rs_[4], rq_[4];
  const int wv = tid >> 6;
  if ((tid & 63) == 0) { rs_[wv] = sum; rq_[wv] = sq; }
  __syncthreads();
  sum = rs_[0] + rs_[1] + rs_[2] + rs_[3];
  sq  = rq_[0] + rq_[1] + rq_[2] + rq_[3];
  const float mu  = sum * (1.f / HID);
  const float var = sq * (1.f / HID) - mu * mu;
  const float inv = rsqrtf(var + 1e-12f);
#pragma unroll
  for (int j = 0; j < 3; j++) {
    int c = tid + j * 256;
    float o = (v[j] - mu) * inv * g[c] + be[c];
    h[(size_t)tok * HID + c] = (__bf16)o;
  }
}

// ---------------- all-layer M transpose+convert: Mt[l][h][t][s] = bf16(M[l][h][s][t]) ----------------
__global__ __launch_bounds__(256) void transpose_all_m_k(
    const float* __restrict__ M, __bf16* __restrict__ Mt) {
  __shared__ float tile[64][68];            // +4 pad
  const int lh = blockIdx.z;                // layer*HEADS + head
  const int t0 = blockIdx.x * 64, s0 = blockIdx.y * 64;
  const float* src = M + (size_t)lh * SEQ * SEQ;
  __bf16* dst = Mt + (size_t)lh * SEQ * SEQ;
  const int tid = threadIdx.x;
#pragma unroll
  for (int it = 0; it < 4; it++) {
    int e = (it * 256 + tid) * 4;
    int r = e >> 6, c = e & 63;             // tile[r=s][c=t]
    *(f32x4*)&tile[r][c] = *(const f32x4*)&src[(size_t)(s0 + r) * SEQ + t0 + c];
  }
  __syncthreads();
#pragma unroll
  for (int it = 0; it < 2; it++) {
    int e = (it * 256 + tid) * 8;
    int r = e >> 6, c = e & 63;
    bf16x8 vv;
#pragma unroll
    for (int j = 0; j < 8; j++) vv[j] = (__bf16)tile[c + j][r];
    *(bf16x8*)&dst[(size_t)(t0 + r) * SEQ + s0 + c] = vv;
  }
}

// ---------------- flipped dense: h2t[dout][tok] = sum_k Wb[dout][k]*h[tok][k] ----------------
__global__ __launch_bounds__(256) void dense_t_k(
    const __bf16* __restrict__ Wb, const __bf16* __restrict__ hin,
    __bf16* __restrict__ h2t) {
  __shared__ __bf16 Al[128 * 32];           // unpadded, 64 B rows (global_load_lds layout)
  __shared__ __bf16 Bl[128 * 32];
  const int n0 = blockIdx.x * 128;          // token base
  const int m0 = blockIdx.y * 128;          // dout base
  const int tid = threadIdx.x;
  const int wave = tid >> 6, lane = tid & 63;
  const int wm = (wave >> 1) << 6, wn = (wave & 1) << 6;
  const int lm = lane & 15, q = lane >> 4;
  const int lrow = lane >> 2, lcol = (lane & 3) * 8;  // staging: 4 lanes/row
  f32x4 acc[4][4];
#pragma unroll
  for (int i = 0; i < 4; i++)
#pragma unroll
    for (int j = 0; j < 4; j++) acc[i][j] = {0.f, 0.f, 0.f, 0.f};

  for (int k0 = 0; k0 < HID; k0 += 32) {
    // 8192 B per matrix = 8 chunks x 1024 B; wave w -> chunks {2w,2w+1} of each
#pragma unroll
    for (int it = 0; it < 2; it++) {
      int c = wave * 2 + it;                // chunk: rows [16c,16c+16)
      int row = c * 16 + lrow;
      async_cp16(&Wb[(size_t)(m0 + row) * HID + k0 + lcol], &Al[c * 512 + lane * 8]);
      async_cp16(&hin[(size_t)(n0 + row) * HID + k0 + lcol], &Bl[c * 512 + lane * 8]);
    }
    __syncthreads();
    bf16x8 af[4], bfr[4];
#pragma unroll
    for (int i = 0; i < 4; i++) {
      af[i]  = *(const bf16x8*)&Al[(wm + i * 16 + lm) * 32 + q * 8];
      bfr[i] = *(const bf16x8*)&Bl[(wn + i * 16 + lm) * 32 + q * 8];
    }
#pragma unroll
    for (int mi = 0; mi < 4; mi++)
#pragma unroll
      for (int ni = 0; ni < 4; ni++)
        acc[mi][ni] = __builtin_amdgcn_mfma_f32_16x16x32_bf16(af[mi], bfr[ni], acc[mi][ni], 0, 0, 0);
    __syncthreads();
  }
  // D layout: row(m)=q*4+r, col(n)=lm  [m89/m91]
#pragma unroll
  for (int mi = 0; mi < 4; mi++)
#pragma unroll
    for (int ni = 0; ni < 4; ni++)
#pragma unroll
      for (int r = 0; r < 4; r++) {
        int dout = m0 + wm + mi * 16 + q * 4 + r;
        int n = n0 + wn + ni * 16 + lm;
        h2t[(size_t)dout * TOK + n] = (__bf16)acc[mi][ni][r];
      }
}

// ---------------- mixing + bias + relu ----------------
// C[t][d] = sum_s Mt[lh][t][s] * h2t[head*64+d][b*512+s];  hout[b][t][head*64+d]=relu(C+bias)
__global__ __launch_bounds__(256) void mix_relu_k(
    const __bf16* __restrict__ Mtl, const __bf16* __restrict__ h2t,
    const float* __restrict__ bias_l, __bf16* __restrict__ hout) {
  __shared__ __bf16 Al[256 * 32];           // Mt rows (m = t), unpadded
  __shared__ __bf16 Bl[64 * 32];            // h2t rows (n = d)
  const int t0 = blockIdx.x * 256;
  const int head = blockIdx.y;
  const int b = blockIdx.z;
  const __bf16* Mh = Mtl + (size_t)head * SEQ * SEQ;
  const __bf16* X  = h2t + (size_t)head * DH * TOK + (size_t)b * SEQ;
  const int tid = threadIdx.x;
  const int wave = tid >> 6, lane = tid & 63;
  const int wm = wave << 6;                 // 4 waves x 64 t-rows
  const int lm = lane & 15, q = lane >> 4;
  const int lrow = lane >> 2, lcol = (lane & 3) * 8;
  f32x4 acc[4][4];
#pragma unroll
  for (int i = 0; i < 4; i++)
#pragma unroll
    for (int j = 0; j < 4; j++) acc[i][j] = {0.f, 0.f, 0.f, 0.f};

  for (int s0 = 0; s0 < SEQ; s0 += 32) {
    // A: 16 KB = 16 chunks; wave w -> chunks 4w..4w+3.  B: 4 KB = 4 chunks; wave w -> chunk w.
#pragma unroll
    for (int it = 0; it < 4; it++) {
      int c = wave * 4 + it;
      int row = c * 16 + lrow;
      async_cp16(&Mh[(size_t)(t0 + row) * SEQ + s0 + lcol], &Al[c * 512 + lane * 8]);
    }
    {
      int row = wave * 16 + lrow;
      async_cp16(&X[(size_t)row * TOK + s0 + lcol], &Bl[wave * 512 + lane * 8]);
    }
    __syncthreads();
    bf16x8 af[4], bfr[4];
#pragma unroll
    for (int i = 0; i < 4; i++) {
      af[i]  = *(const bf16x8*)&Al[(wm + i * 16 + lm) * 32 + q * 8];
      bfr[i] = *(const bf16x8*)&Bl[(i * 16 + lm) * 32 + q * 8];
    }
#pragma unroll
    for (int mi = 0; mi < 4; mi++)
#pragma unroll
      for (int ni = 0; ni < 4; ni++)
        acc[mi][ni] = __builtin_amdgcn_mfma_f32_16x16x32_bf16(af[mi], bfr[ni], acc[mi][ni], 0, 0, 0);
    __syncthreads();
  }
  float bias[4];
#pragma unroll
  for (int ni = 0; ni < 4; ni++) bias[ni] = bias_l[head * DH + ni * 16 + lm];
#pragma unroll
  for (int mi = 0; mi < 4; mi++)
#pragma unroll
    for (int ni = 0; ni < 4; ni++)
#pragma unroll
      for (int r = 0; r < 4; r++) {
        int t = t0 + wm + mi * 16 + q * 4 + r;
        float vv = fmaxf(acc[mi][ni][r] + bias[ni], 0.f);
        hout[((size_t)b * SEQ + t) * HID + head * DH + ni * 16 + lm] = (__bf16)vv;
      }
}

// ---------------- final dense: out[tok][dout] = sum_k h[tok][k]*lwb[dout][k] + lb (fp32 out) ----------------
__global__ __launch_bounds__(256) void dense_nat_k(
    const __bf16* __restrict__ hin, const __bf16* __restrict__ lwb,
    const float* __restrict__ lb, float* __restrict__ out) {
  __shared__ __bf16 Al[128 * 32];
  __shared__ __bf16 Bl[128 * 32];
  const int m0 = blockIdx.x * 128;
  const int n0 = blockIdx.y * 128;
  const int tid = threadIdx.x;
  const int wave = tid >> 6, lane = tid & 63;
  const int wm = (wave >> 1) << 6, wn = (wave & 1) << 6;
  const int lm = lane & 15, q = lane >> 4;
  const int lrow = lane >> 2, lcol = (lane & 3) * 8;
  f32x4 acc[4][4];
#pragma unroll
  for (int i = 0; i < 4; i++)
#pragma unroll
    for (int j = 0; j < 4; j++) acc[i][j] = {0.f, 0.f, 0.f, 0.f};

  for (int k0 = 0; k0 < HID; k0 += 32) {
#pragma unroll
    for (int it = 0; it < 2; it++) {
      int c = wave * 2 + it;
      int row = c * 16 + lrow;
      async_cp16(&hin[(size_t)(m0 + row) * HID + k0 + lcol], &Al[c * 512 + lane * 8]);
      async_cp16(&lwb[(size_t)(n0 + row) * HID + k0 + lcol], &Bl[c * 512 + lane * 8]);
    }
    __syncthreads();
    bf16x8 af[4], bfr[4];
#pragma unroll
    for (int i = 0; i < 4; i++) {
      af[i]  = *(const bf16x8*)&Al[(wm + i * 16 + lm) * 32 + q * 8];
      bfr[i] = *(const bf16x8*)&Bl[(wn + i * 16 + lm) * 32 + q * 8];
    }
#pragma unroll
    for (int mi = 0; mi < 4; mi++)
#pragma unroll
      for (int ni = 0; ni < 4; ni++)
        acc[mi][ni] = __builtin_amdgcn_mfma_f32_16x16x32_bf16(af[mi], bfr[ni], acc[mi][ni], 0, 0, 0);
    __syncthreads();
  }
#pragma unroll
  for (int mi = 0; mi < 4; mi++)
#pragma unroll
    for (int ni = 0; ni < 4; ni++) {
      float bias = lb[n0 + wn + ni * 16 + lm];
#pragma unroll
      for (int r = 0; r < 4; r++) {
        int tok = m0 + wm + mi * 16 + q * 4 + r;
        int n = n0 + wn + ni * 16 + lm;
        out[(size_t)tok * HID + n] = acc[mi][ni][r] + bias;
      }
    }
}

extern "C" void kernel_launch(void* const* d_in, const int* in_sizes, int n_in,
                              void* d_out, int out_size, void* d_ws, size_t ws_size,
                              hipStream_t stream) {
  const int*   x   = (const int*)d_in[0];
  const float* we  = (const float*)d_in[1];
  const float* pe  = (const float*)d_in[2];
  const float* te  = (const float*)d_in[3];
  const float* lng = (const float*)d_in[4];
  const float* lnb = (const float*)d_in[5];
  const float* W   = (const float*)d_in[6];   // [12][768][768] fp32
  const float* bb  = (const float*)d_in[7];   // [12][768] fp32
  const float* M   = (const float*)d_in[8];   // [12][12][512][512] fp32
  const float* lw  = (const float*)d_in[9];
  const float* lb  = (const float*)d_in[10];

  // workspace (bf16), ~141 MB total (ws ~600 MB per fill WRITE_SIZE):
  __bf16* Mt  = (__bf16*)d_ws;                            // 12*12*512*512 = 75.5 MB
  __bf16* Wb  = Mt + (size_t)LAYERS * HEADS * SEQ * SEQ;  // 12*768*768    = 14.2 MB
  __bf16* lwb = Wb + (size_t)LAYERS * HID * HID;          // 768*768       = 1.2 MB
  __bf16* hA  = lwb + (size_t)HID * HID;                  // 16384*768     = 25.2 MB
  __bf16* h2t = hA + (size_t)TOK * HID;                   // 16384*768     = 25.2 MB
  float* out = (float*)d_out;

  convert_k<<<LAYERS * HID * HID / 1024, 256, 0, stream>>>(W, Wb);
  convert_k<<<HID * HID / 1024, 256, 0, stream>>>(lw, lwb);
  transpose_all_m_k<<<dim3(8, 8, LAYERS * HEADS), 256, 0, stream>>>(M, Mt);
  embed_ln_k<<<TOK, 256, 0, stream>>>(x, we, pe, te, lng, lnb, hA);
  for (int l = 0; l < LAYERS; l++) {
    dense_t_k<<<dim3(TOK / 128, HID / 128), 256, 0, stream>>>(Wb + (size_t)l * HID * HID, hA, h2t);
    mix_relu_k<<<dim3(2, HEADS, BATCH), 256, 0, stream>>>(Mt + (size_t)l * HEADS * SEQ * SEQ, h2t,
                                                          bb + (size_t)l * HID, hA);
  }
  dense_nat_k<<<dim3(TOK / 128, HID / 128), 256, 0, stream>>>(hA, lwb, lb, out);
}